// Round 6
// baseline (3266.164 us; speedup 1.0000x reference)
//
#include <hip/hip_runtime.h>
#include <math.h>

#define T_ 16
#define B_ 128
#define C3 24
#define OUT_ 64
#define NT 768
#define EPS_ 1e-5f
#define TPs 776      // s_tP row stride (dwords)
#define T2S 66       // s_t2 per-d stride (shorts) — odd-dword => conflict-free
#define PS 6144      // P chunk: 16d * 48r * 8j shorts

typedef __attribute__((ext_vector_type(8))) short bf16x8;
typedef __attribute__((ext_vector_type(4))) float f32x4;

union FragU { unsigned u[4]; bf16x8 f; };

__device__ __forceinline__ short f2bf(float x) {
    unsigned u = __float_as_uint(x);
    return (short)((u + 0x7fffu + ((u >> 16) & 1u)) >> 16);
}
// fp32 -> (bf16_hi << 16) | bf16_lo(residual), both RNE
__device__ __forceinline__ unsigned packsplit(float x) {
    unsigned u = __float_as_uint(x);
    unsigned h = (u + 0x7fffu + ((u >> 16) & 1u)) & 0xffff0000u;
    float r = x - __uint_as_float(h);
    unsigned v = __float_as_uint(r);
    unsigned l = (v + 0x7fffu + ((v >> 16) & 1u)) >> 16;
    return h | l;
}
__device__ __forceinline__ void unpack_frags(const unsigned* p, bf16x8& hi, bf16x8& lo) {
    FragU H, L;
#pragma unroll
    for (int q = 0; q < 4; ++q) {
        H.u[q] = (p[2*q] >> 16) | (p[2*q+1] & 0xffff0000u);
        L.u[q] = (p[2*q] & 0xffffu) | (p[2*q+1] << 16);
    }
    hi = H.f; lo = L.f;
}
__device__ __forceinline__ f32x4 mfma16(bf16x8 a, bf16x8 b, f32x4 c) {
    return __builtin_amdgcn_mfma_f32_16x16x32_bf16(a, b, c, 0, 0, 0);
}

// ---------- prep: Wr -> A-fragment-major hi/lo planes ----------
// A[m=(d*96+r)][e] = Wr[d*96+e][r].  idx = ((mt*3+kb)*64+lane)*8+jj,
// mt = d*6+rt (576), element = Wr[(d*96 + kb*32+grp*8+jj)][rt*16+col]
__global__ void prep_wrA(const float* __restrict__ Wr, short* __restrict__ H, short* __restrict__ L) {
    int idx = blockIdx.x * 256 + threadIdx.x;
    if (idx >= 884736) return;
    int jj = idx & 7;
    int lane = (idx >> 3) & 63;
    int kb = (idx >> 9) % 3;
    int mt = idx / 1536;
    int col = lane & 15, grp = lane >> 4;
    int d = mt / 6, rt = mt % 6;
    int e = kb * 32 + grp * 8 + jj;
    int r = rt * 16 + col;
    float x = Wr[(size_t)(d * 96 + e) * 96 + r];
    unsigned u = __float_as_uint(x);
    unsigned hb = (u + 0x7fffu + ((u >> 16) & 1u)) & 0xffff0000u;
    float res = x - __uint_as_float(hb);
    unsigned v = __float_as_uint(res);
    H[idx] = (short)(hb >> 16);
    L[idx] = (short)((v + 0x7fffu + ((v >> 16) & 1u)) >> 16);
}
// ---------- prep: W2 -> B-fragment-major hi/lo planes (unchanged) ----------
__global__ void prep_w2f(const float* __restrict__ W2, short* __restrict__ Fhi, short* __restrict__ Flo) {
    int idx = blockIdx.x * 256 + threadIdx.x;
    if (idx >= 73728) return;
    int j = idx & 7, lane = (idx >> 3) & 63, kb = (idx >> 9) % 24, rt = idx / (512 * 24);
    int col = lane & 15, grp = lane >> 4;
    int f = rt * 16 + col, k = kb * 32 + grp * 8 + j;
    float x = W2[(size_t)k * 96 + f];
    unsigned u = __float_as_uint(x);
    unsigned h = (u + 0x7fffu + ((u >> 16) & 1u)) & 0xffff0000u;
    float res = x - __uint_as_float(h);
    unsigned v = __float_as_uint(res);
    Fhi[idx] = (short)(h >> 16);
    Flo[idx] = (short)((v + 0x7fffu + ((v >> 16) & 1u)) >> 16);
}
__global__ __launch_bounds__(NT, 1) void y0_kernel(const float* __restrict__ rel_bias,
                                                   const float* __restrict__ Wr,
                                                   float* __restrict__ y0) {
    __shared__ float s[NT];
    const int n = blockIdx.x;
    const int tid = threadIdx.x;
    const int r = tid % 96, p = tid / 96;
    const float* rb = rel_bias + n * 9216;
    float acc = 0.f;
    for (int i = p * 1152; i < (p + 1) * 1152; ++i)
        acc += rb[i] * Wr[(size_t)i * 96 + r];
    s[tid] = acc;
    __syncthreads();
    if (tid < 96) {
        float tot = 0.f;
        for (int q = 0; q < 8; ++q) tot += s[q * 96 + tid];
        y0[n * 96 + tid] = tot;
    }
}

// ---------------- main scan: 2 blocks per batch (r-split heavy) ----------------
__global__ __launch_bounds__(NT, 3) void stm_kernel(
    const float* __restrict__ x, const float* __restrict__ Wqkv, const float* __restrict__ bqkv,
    const float* __restrict__ ln_g, const float* __restrict__ ln_b,
    const float* __restrict__ a1p, const float* __restrict__ a2p, const float* __restrict__ a3p,
    const float* __restrict__ b2, const float* __restrict__ br,
    const float* __restrict__ W3, const float* __restrict__ b3,
    const float* __restrict__ item_bias, const float* __restrict__ rel_bias,
    const float* __restrict__ y0g,
    const short* __restrict__ WrAH, const short* __restrict__ WrAL,
    const short* __restrict__ W2H, const short* __restrict__ W2L,
    float* __restrict__ out)
{
    __shared__ float s_Q[2304];
    __shared__ __attribute__((aligned(16))) unsigned s_scr[2304];
    __shared__ __attribute__((aligned(16))) unsigned s_tP[8 * TPs]; // split t: [j][n*96+d]
    __shared__ __attribute__((aligned(16))) short s_t2[96 * T2S];   // hi-bf16 t: [d][n][j]
    __shared__ __attribute__((aligned(16))) short s_P[2 * PS];      // P chunks [dl][r][j]
    __shared__ float s_tsum[768];
    __shared__ float s_v[768];
    __shared__ float s_G[768];
    __shared__ float s_y[384];           // [n][48] this block's half
    __shared__ float s_xt[96];
    __shared__ float s_xtWq[24];
    __shared__ float s_GWq[192];
    __shared__ float s_b2Wq[24];
    __shared__ float s_Vtr[96];
    __shared__ float s_br[96];
    __shared__ float s_red[32];
    __shared__ float s_mu, s_rstd;

    const int tid = threadIdx.x;
    const int b = blockIdx.x >> 1;
    const int h = blockIdx.x & 1;        // r-half: r in [48h, 48h+48)
    const int wv = tid >> 6, lane = tid & 63, col = lane & 15, grp = lane >> 4;
    const float a1 = a1p[0], a2 = a2p[0], a3 = a3p[0];
    float* scr = (float*)s_scr;

    // register-resident Mi/S
    const int de = tid >> 3, ef0 = (tid & 7) * 12;
    float rMi[12], rS[12], rb2[12];
#pragma unroll
    for (int ii = 0; ii < 12; ++ii) {
        rMi[ii] = item_bias[de * 96 + ef0 + ii];
        float ss = 0.f;
        for (int n = 0; n < 8; ++n) ss += rel_bias[n * 9216 + de * 96 + ef0 + ii];
        rS[ii] = ss;
        rb2[ii] = b2[ef0 + ii];
    }

    // ---- init ----
    if (tid < 384) s_y[tid] = y0g[(tid / 48) * 96 + h * 48 + (tid % 48)];
    if (tid < 96) s_br[tid] = br[tid];
    for (int pp = 0; pp < 3; ++pp) {
        int o = tid + NT * pp; int i = o / C3, c = o % C3;
        float acc = 0.f;
        const float* ib = item_bias + i * 96;
        for (int k = 0; k < 96; ++k) acc += ib[k] * Wqkv[k * C3 + c];
        s_Q[o] = acc;
    }
    { int c = tid % C3, p = tid / C3; float acc = 0.f;
      for (int k = 3 * p; k < 3 * p + 3; ++k) acc += b2[k] * Wqkv[k * C3 + c];
      scr[tid] = acc; }
    __syncthreads();
    if (tid < C3) { float a = 0.f; for (int p = 0; p < 32; ++p) a += scr[p * C3 + tid]; s_b2Wq[tid] = a; }
    __syncthreads();

    for (int t = 0; t < T_; ++t) {
        // 1: xt
        if (tid < 96) s_xt[tid] = x[((size_t)t * B_ + b) * 96 + tid];
        __syncthreads();
        // 2: Mi += xt xt^T (regs) ; xtWq partials
        {
            float xde = s_xt[de];
            const float4* xp = (const float4*)&s_xt[ef0];
            float4 x0 = xp[0], x1 = xp[1], x2 = xp[2];
            rMi[0] += xde * x0.x; rMi[1] += xde * x0.y; rMi[2] += xde * x0.z; rMi[3] += xde * x0.w;
            rMi[4] += xde * x1.x; rMi[5] += xde * x1.y; rMi[6] += xde * x1.z; rMi[7] += xde * x1.w;
            rMi[8] += xde * x2.x; rMi[9] += xde * x2.y; rMi[10] += xde * x2.z; rMi[11] += xde * x2.w;
        }
        { int c = tid % C3, p = tid / C3; float acc = 0.f;
          for (int k = 3 * p; k < 3 * p + 3; ++k) acc += s_xt[k] * Wqkv[k * C3 + c];
          scr[tid] = acc; }
        __syncthreads();
        // 3: xtWq final ; Vtr partials (register products + shfl reduce)
        if (tid < C3) { float a = 0.f; for (int p = 0; p < 32; ++p) a += scr[p * C3 + tid]; s_xtWq[tid] = a; }
        {
            float p12[12];
#pragma unroll
            for (int ii = 0; ii < 12; ++ii) p12[ii] = rMi[ii] * rS[ii];
#pragma unroll
            for (int ii = 0; ii < 12; ++ii) {
                p12[ii] += __shfl_xor(p12[ii], 8);
                p12[ii] += __shfl_xor(p12[ii], 16);
                p12[ii] += __shfl_xor(p12[ii], 32);
            }
            if ((lane >> 3) == 0) {
#pragma unroll
                for (int ii = 0; ii < 12; ++ii)
                    scr[768 + wv * 96 + (lane & 7) * 12 + ii] = p12[ii];
            }
        }
        __syncthreads();
        // 4: Vtr final ; Q += xt ⊗ xtWq
        if (tid < 96) { float a = 0.f; for (int w = 0; w < 12; ++w) a += scr[768 + w * 96 + tid]; s_Vtr[tid] = a; }
        for (int pp = 0; pp < 3; ++pp) { int o = tid + NT * pp; int i = o / C3, c = o % C3;
            s_Q[o] += s_xt[i] * s_xtWq[c]; }
        __syncthreads();
        // 5: qkv_pre -> scr[0..2304) + LN sums
        {
            float ls = 0.f, lq = 0.f;
            for (int pp = 0; pp < 3; ++pp) {
                int o = tid + NT * pp; int i = o / C3, c = o % C3;
                float q = s_Q[o] + a2 * s_Vtr[i] * s_xtWq[c] + bqkv[c];
                scr[o] = q; ls += q; lq += q * q;
            }
            for (int off = 32; off > 0; off >>= 1) { ls += __shfl_down(ls, off); lq += __shfl_down(lq, off); }
            if (lane == 0) { s_red[wv] = ls; s_red[16 + wv] = lq; }
        }
        __syncthreads();
        if (tid == 0) {
            float S = 0.f, Qs = 0.f;
            for (int w = 0; w < 12; ++w) { S += s_red[w]; Qs += s_red[16 + w]; }
            float mu = S * (1.0f / 2304.f);
            float var = Qs * (1.0f / 2304.f) - mu * mu;
            s_mu = mu; s_rstd = rsqrtf(var + EPS_);
        }
        __syncthreads();
        // 7: LN apply
        { float mu = s_mu, rs = s_rstd;
          for (int pp = 0; pp < 3; ++pp) { int o = tid + NT * pp;
              scr[o] = (scr[o] - mu) * rs * ln_g[o] + ln_b[o]; } }
        __syncthreads();
        // 8: v copy + t: fp32 tanh, exact tsum, split store (G-GEMM) + hi store (GEMM-2 A)
        { int j = tid / 96, e = tid % 96; s_v[tid] = scr[e * C3 + 16 + j]; }
        {
            int j = tid / 96, d = tid % 96;
            float kk = scr[d * C3 + 8 + j];
            float ts = 0.f;
#pragma unroll
            for (int n = 0; n < 8; ++n) {
                float tv = tanhf(scr[d * C3 + n] * kk);
                ts += tv;
                unsigned p = packsplit(tv);
                s_tP[j * TPs + n * 96 + d] = p;
                s_t2[d * T2S + n * 8 + j] = (short)(p >> 16);
            }
            s_tsum[j * 96 + d] = ts;
        }
        __syncthreads();
        // 9: G-GEMM (4-term split, recurrence-critical, unchanged)
        {
            const int rt = wv % 6, kh = wv / 6;
            f32x4 accG = {0.f, 0.f, 0.f, 0.f};
#pragma unroll
            for (int s2 = 0; s2 < 12; ++s2) {
                int kb = kh * 12 + s2;
                unsigned pa[8] = {0,0,0,0,0,0,0,0};
                if (col < 8) {
                    const uint4* q0 = (const uint4*)&s_tP[col * TPs + kb * 32 + grp * 8];
                    uint4 x0 = q0[0], x1 = q0[1];
                    pa[0]=x0.x; pa[1]=x0.y; pa[2]=x0.z; pa[3]=x0.w;
                    pa[4]=x1.x; pa[5]=x1.y; pa[6]=x1.z; pa[7]=x1.w;
                }
                bf16x8 ah, al; unpack_frags(pa, ah, al);
                int fo = ((rt * 24 + kb) * 64 + lane) * 8;
                bf16x8 bh = *(const bf16x8*)&W2H[fo];
                bf16x8 bl = *(const bf16x8*)&W2L[fo];
                accG = mfma16(ah, bh, accG);
                accG = mfma16(al, bh, accG);
                accG = mfma16(ah, bl, accG);
                accG = mfma16(al, bl, accG);
            }
            if (kh == 0 && grp < 2) {
#pragma unroll
                for (int reg = 0; reg < 4; ++reg)
                    s_G[(grp * 4 + reg) * 96 + rt * 16 + col] = accG[reg];
            }
            __syncthreads();
            if (kh == 1 && grp < 2) {
#pragma unroll
                for (int reg = 0; reg < 4; ++reg)
                    s_G[(grp * 4 + reg) * 96 + rt * 16 + col] += accG[reg];
            }
        }
        __syncthreads();
        // 10: GWq partials + S/Mi register updates
        { int oo = tid % 192, p = tid / 192; int jg = oo / C3, cc = oo % C3;
          float a = 0.f;
          for (int f = p * 24; f < p * 24 + 24; ++f) a += s_G[jg * 96 + f] * Wqkv[f * C3 + cc];
          scr[tid] = a; }
        {
            float tj[8], vj[8];
#pragma unroll
            for (int j = 0; j < 8; ++j) { tj[j] = s_tsum[j * 96 + de]; vj[j] = s_v[j * 96 + de]; }
            float sn[12], r2[12];
#pragma unroll
            for (int ii = 0; ii < 12; ++ii) { sn[ii] = 0.f; r2[ii] = rb2[ii]; }
#pragma unroll
            for (int j = 0; j < 8; ++j) {
                const float4* vp = (const float4*)&s_v[j * 96 + ef0];
                const float4* gp = (const float4*)&s_G[j * 96 + ef0];
#pragma unroll
                for (int q4 = 0; q4 < 3; ++q4) {
                    float4 vv = vp[q4], gg = gp[q4];
                    sn[q4 * 4 + 0] += tj[j] * vv.x; sn[q4 * 4 + 1] += tj[j] * vv.y;
                    sn[q4 * 4 + 2] += tj[j] * vv.z; sn[q4 * 4 + 3] += tj[j] * vv.w;
                    r2[q4 * 4 + 0] += vj[j] * gg.x; r2[q4 * 4 + 1] += vj[j] * gg.y;
                    r2[q4 * 4 + 2] += vj[j] * gg.z; r2[q4 * 4 + 3] += vj[j] * gg.w;
                }
            }
#pragma unroll
            for (int ii = 0; ii < 12; ++ii) {
                rS[ii] = a1 * rS[ii] + sn[ii];
                rMi[ii] += a3 * r2[ii];
            }
        }
        __syncthreads();
        // 11: GWq final
        if (tid < 192) s_GWq[tid] = scr[tid] + scr[192 + tid] + scr[384 + tid] + scr[576 + tid];
        __syncthreads();
        // 12: Q += a3*(v^T GWq + b2Wq)
        for (int pp = 0; pp < 3; ++pp) {
            int o = tid + NT * pp; int i = o / C3, c = o % C3;
            float a = s_b2Wq[c];
#pragma unroll
            for (int j = 0; j < 8; ++j) a += s_v[j * 96 + i] * s_GWq[j * C3 + c];
            s_Q[o] += a3 * a;
        }
        // ---- heavy: y += t·(v·Wr) as two MFMA GEMMs ----
        // B1 fragments (v, bf16), shared by all GEMM-1 tiles this step
        bf16x8 Bv[3];
#pragma unroll
        for (int kb = 0; kb < 3; ++kb) {
            FragU F;
            if (col < 8) {
                const float* vp = &s_v[col * 96 + kb * 32 + grp * 8];
#pragma unroll
                for (int q = 0; q < 4; ++q)
                    F.u[q] = (unsigned)(unsigned short)f2bf(vp[2 * q]) |
                             ((unsigned)(unsigned short)f2bf(vp[2 * q + 1]) << 16);
            } else { F.u[0] = F.u[1] = F.u[2] = F.u[3] = 0; }
            Bv[kb] = F.f;
        }
        const int nt = wv >> 2, g = wv & 3;
        f32x4 accY = {0.f, 0.f, 0.f, 0.f};

        auto buildP = [&](int dblk, int buf) {
            short* dst = s_P + buf * PS;
#pragma unroll
            for (int i = 0; i < 4; ++i) {
                int idx = wv + 12 * i;
                int dl = idx / 3, rtl = idx % 3;
                int mt = (dblk * 16 + dl) * 6 + 3 * h + rtl;
                f32x4 a = {0.f, 0.f, 0.f, 0.f};
#pragma unroll
                for (int kb = 0; kb < 3; ++kb) {
                    size_t fo = ((size_t)(mt * 3 + kb) * 64 + lane) * 8;
                    bf16x8 Ah = *(const bf16x8*)&WrAH[fo];
                    bf16x8 Al = *(const bf16x8*)&WrAL[fo];
                    a = mfma16(Ah, Bv[kb], a);
                    a = mfma16(Al, Bv[kb], a);
                }
                if (col < 8) {
#pragma unroll
                    for (int reg = 0; reg < 4; ++reg) {
                        int rl = rtl * 16 + grp * 4 + reg;
                        dst[(dl * 48 + rl) * 8 + col] = f2bf(a[reg]);
                    }
                }
            }
        };

        buildP(0, 0);
        for (int dblk = 0; dblk < 6; ++dblk) {
            __syncthreads();
            {
                FragU A;
                if (col < 8) {
                    const unsigned* t2d = (const unsigned*)s_t2;
                    int bi = (dblk * 16 + g * 4 + grp) * 33 + col * 4;
                    A.u[0] = t2d[bi]; A.u[1] = t2d[bi + 1]; A.u[2] = t2d[bi + 2]; A.u[3] = t2d[bi + 3];
                } else { A.u[0] = A.u[1] = A.u[2] = A.u[3] = 0; }
                bf16x8 B2 = *(const bf16x8*)&s_P[(dblk & 1) * PS + ((g * 4 + grp) * 48 + nt * 16 + col) * 8];
                accY = mfma16(A.f, B2, accY);
            }
            if (dblk < 5) buildP(dblk + 1, (dblk + 1) & 1);
        }
        __syncthreads();
        // y reduce: 4 g-partials per (n, r)
        if (grp < 2) {
#pragma unroll
            for (int reg = 0; reg < 4; ++reg)
                scr[g * 384 + (grp * 4 + reg) * 48 + nt * 16 + col] = accY[reg];
        }
        __syncthreads();
        if (tid < 384)
            s_y[tid] = a1 * s_y[tid] + scr[tid] + scr[384 + tid] + scr[768 + tid] + scr[1152 + tid];
        __syncthreads();
        // out partial: this block's 384 (n,rl), atomicAdd combine
        {
            int o = tid & 63, qq = tid >> 6;
            float a = 0.f;
            for (int il = qq * 32; il < qq * 32 + 32; ++il) {
                int n = il / 48, rl = il % 48;
                a += (s_y[il] + s_br[h * 48 + rl]) * W3[(size_t)(n * 96 + h * 48 + rl) * 64 + o];
            }
            scr[tid] = a;
        }
        __syncthreads();
        if (tid < 64) {
            float a = (h == 0) ? b3[tid] : 0.f;
            for (int q = 0; q < 12; ++q) a += scr[q * 64 + tid];
            atomicAdd(&out[((size_t)t * B_ + b) * OUT_ + tid], a);
        }
        __syncthreads();
    }
}

extern "C" void kernel_launch(void* const* d_in, const int* in_sizes, int n_in,
                              void* d_out, int out_size, void* d_ws, size_t ws_size,
                              hipStream_t stream) {
    const float* x         = (const float*)d_in[0];
    const float* Wqkv      = (const float*)d_in[1];
    const float* bqkv      = (const float*)d_in[2];
    const float* ln_g      = (const float*)d_in[3];
    const float* ln_b      = (const float*)d_in[4];
    const float* a1        = (const float*)d_in[5];
    const float* a2        = (const float*)d_in[6];
    const float* a3        = (const float*)d_in[7];
    const float* W2        = (const float*)d_in[8];
    const float* b2        = (const float*)d_in[9];
    const float* Wr        = (const float*)d_in[10];
    const float* br        = (const float*)d_in[11];
    const float* W3        = (const float*)d_in[12];
    const float* b3        = (const float*)d_in[13];
    const float* item_bias = (const float*)d_in[14];
    const float* rel_bias  = (const float*)d_in[15];
    float* out = (float*)d_out;

    char* ws = (char*)d_ws;
    short* WrAH = (short*)ws;                               // 1,769,472 B
    short* WrAL = (short*)(ws + 1769472);                   // 1,769,472 B
    short* W2H  = (short*)(ws + 2 * 1769472);               //   147,456 B
    short* W2L  = (short*)(ws + 2 * 1769472 + 147456);      //   147,456 B
    float* y0   = (float*)(ws + 2 * 1769472 + 2 * 147456);  //     3,072 B

    hipMemsetAsync(out, 0, (size_t)out_size * sizeof(float), stream);
    hipLaunchKernelGGL(prep_wrA, dim3(3456), dim3(256), 0, stream, Wr, WrAH, WrAL);
    hipLaunchKernelGGL(prep_w2f, dim3(288), dim3(256), 0, stream, W2, W2H, W2L);
    hipLaunchKernelGGL(y0_kernel, dim3(8), dim3(NT), 0, stream, rel_bias, Wr, y0);
    hipLaunchKernelGGL(stm_kernel, dim3(2 * B_), dim3(NT), 0, stream,
                       x, Wqkv, bqkv, ln_g, ln_b, a1, a2, a3,
                       b2, br, W3, b3, item_bias, rel_bias,
                       y0, WrAH, WrAL, W2H, W2L, out);
}

// Round 7
// 1389.801 us; speedup vs baseline: 2.3501x; 2.3501x over previous
//
#include <hip/hip_runtime.h>
#include <math.h>

#define T_ 16
#define B_ 128
#define C3 24
#define OUT_ 64
#define NT 768
#define EPS_ 1e-5f
#define TPs 776      // s_tP row stride (dwords)

typedef __attribute__((ext_vector_type(8))) short bf16x8;
typedef __attribute__((ext_vector_type(4))) float f32x4;

union FragU { unsigned u[4]; bf16x8 f; };

__device__ __forceinline__ short f2bf(float x) {
    unsigned u = __float_as_uint(x);
    return (short)((u + 0x7fffu + ((u >> 16) & 1u)) >> 16);
}
// fp32 -> (bf16_hi << 16) | bf16_lo(residual), both RNE
__device__ __forceinline__ unsigned packsplit(float x) {
    unsigned u = __float_as_uint(x);
    unsigned h = (u + 0x7fffu + ((u >> 16) & 1u)) & 0xffff0000u;
    float r = x - __uint_as_float(h);
    unsigned v = __float_as_uint(r);
    unsigned l = (v + 0x7fffu + ((v >> 16) & 1u)) >> 16;
    return h | l;
}
__device__ __forceinline__ void unpack_frags(const unsigned* p, bf16x8& hi, bf16x8& lo) {
    FragU H, L;
#pragma unroll
    for (int q = 0; q < 4; ++q) {
        H.u[q] = (p[2*q] >> 16) | (p[2*q+1] & 0xffff0000u);
        L.u[q] = (p[2*q] & 0xffffu) | (p[2*q+1] << 16);
    }
    hi = H.f; lo = L.f;
}
__device__ __forceinline__ f32x4 mfma16(bf16x8 a, bf16x8 b, f32x4 c) {
    return __builtin_amdgcn_mfma_f32_16x16x32_bf16(a, b, c, 0, 0, 0);
}

// ---------- prep: Wr -> B-fragment-major hi/lo planes, per-d mini-GEMMs ----------
// frag f = d*18 + rt*3 + kf ; element = Wr[(d*96 + kf*32+grp*8+jj)][rt*16+col]
__global__ void prep_wrB(const float* __restrict__ Wr, short* __restrict__ H, short* __restrict__ L) {
    int idx = blockIdx.x * 256 + threadIdx.x;
    if (idx >= 884736) return;
    int jj = idx & 7, lane = (idx >> 3) & 63, f = idx >> 9;
    int kf = f % 3, rt = (f / 3) % 6, d = f / 18;
    int col = lane & 15, grp = lane >> 4;
    int e = kf * 32 + grp * 8 + jj;
    int r = rt * 16 + col;
    float x = Wr[(size_t)(d * 96 + e) * 96 + r];
    unsigned u = __float_as_uint(x);
    unsigned hb = (u + 0x7fffu + ((u >> 16) & 1u)) & 0xffff0000u;
    float res = x - __uint_as_float(hb);
    unsigned v = __float_as_uint(res);
    H[idx] = (short)(hb >> 16);
    L[idx] = (short)((v + 0x7fffu + ((v >> 16) & 1u)) >> 16);
}
// ---------- prep: W2 -> B-fragment-major hi/lo planes (for G-GEMM) ----------
__global__ void prep_w2f(const float* __restrict__ W2, short* __restrict__ Fhi, short* __restrict__ Flo) {
    int idx = blockIdx.x * 256 + threadIdx.x;
    if (idx >= 73728) return;
    int j = idx & 7, lane = (idx >> 3) & 63, kb = (idx >> 9) % 24, rt = idx / (512 * 24);
    int col = lane & 15, grp = lane >> 4;
    int f = rt * 16 + col, k = kb * 32 + grp * 8 + j;
    float x = W2[(size_t)k * 96 + f];
    unsigned u = __float_as_uint(x);
    unsigned h = (u + 0x7fffu + ((u >> 16) & 1u)) & 0xffff0000u;
    float res = x - __uint_as_float(h);
    unsigned v = __float_as_uint(res);
    Fhi[idx] = (short)(h >> 16);
    Flo[idx] = (short)((v + 0x7fffu + ((v >> 16) & 1u)) >> 16);
}
// ---------- prep: y0 = rel_bias @ Wr (fp32) ----------
__global__ __launch_bounds__(NT, 1) void y0_kernel(const float* __restrict__ rel_bias,
                                                   const float* __restrict__ Wr,
                                                   float* __restrict__ y0) {
    __shared__ float s[NT];
    const int n = blockIdx.x;
    const int tid = threadIdx.x;
    const int r = tid % 96, p = tid / 96;
    const float* rb = rel_bias + n * 9216;
    float acc = 0.f;
    for (int i = p * 1152; i < (p + 1) * 1152; ++i)
        acc += rb[i] * Wr[(size_t)i * 96 + r];
    s[tid] = acc;
    __syncthreads();
    if (tid < 96) {
        float tot = 0.f;
        for (int q = 0; q < 8; ++q) tot += s[q * 96 + tid];
        y0[n * 96 + tid] = tot;
    }
}

// ================= Kernel A: recurrence only, 1 block per batch =================
__global__ __launch_bounds__(NT, 3) void stm_rec(
    const float* __restrict__ x, const float* __restrict__ Wqkv, const float* __restrict__ bqkv,
    const float* __restrict__ ln_g, const float* __restrict__ ln_b,
    const float* __restrict__ a1p, const float* __restrict__ a2p, const float* __restrict__ a3p,
    const float* __restrict__ b2,
    const float* __restrict__ item_bias, const float* __restrict__ rel_bias,
    const short* __restrict__ W2H, const short* __restrict__ W2L,
    short* __restrict__ t2g, short* __restrict__ vgb)
{
    __shared__ float s_Q[2304];
    __shared__ __attribute__((aligned(16))) unsigned s_scr[2304];
    __shared__ __attribute__((aligned(16))) unsigned s_tP[8 * TPs]; // split t: [j][n*96+d]
    __shared__ __attribute__((aligned(16))) short s_t2L[6144];      // bf16 t: [n][d*8+j]
    __shared__ float s_tsum[768];
    __shared__ float s_v[768];
    __shared__ float s_G[768];
    __shared__ float s_xt[96];
    __shared__ float s_xtWq[24];
    __shared__ float s_GWq[192];
    __shared__ float s_b2Wq[24];
    __shared__ float s_Vtr[96];
    __shared__ float s_red[32];
    __shared__ float s_mu, s_rstd;

    const int tid = threadIdx.x;
    const int b = blockIdx.x;
    const int wv = tid >> 6, lane = tid & 63, col = lane & 15, grp = lane >> 4;
    const float a1 = a1p[0], a2 = a2p[0], a3 = a3p[0];
    float* scr = (float*)s_scr;

    // register-resident Mi/S: thread owns (de, ef0..ef0+12)
    const int de = tid >> 3, ef0 = (tid & 7) * 12;
    float rMi[12], rS[12], rb2[12];
#pragma unroll
    for (int ii = 0; ii < 12; ++ii) {
        rMi[ii] = item_bias[de * 96 + ef0 + ii];
        float ss = 0.f;
        for (int n = 0; n < 8; ++n) ss += rel_bias[n * 9216 + de * 96 + ef0 + ii];
        rS[ii] = ss;
        rb2[ii] = b2[ef0 + ii];
    }

    // ---- init ----
    for (int pp = 0; pp < 3; ++pp) {
        int o = tid + NT * pp; int i = o / C3, c = o % C3;
        float acc = 0.f;
        const float* ib = item_bias + i * 96;
        for (int k = 0; k < 96; ++k) acc += ib[k] * Wqkv[k * C3 + c];
        s_Q[o] = acc;
    }
    { int c = tid % C3, p = tid / C3; float acc = 0.f;
      for (int k = 3 * p; k < 3 * p + 3; ++k) acc += b2[k] * Wqkv[k * C3 + c];
      scr[tid] = acc; }
    __syncthreads();
    if (tid < C3) { float a = 0.f; for (int p = 0; p < 32; ++p) a += scr[p * C3 + tid]; s_b2Wq[tid] = a; }
    __syncthreads();

    for (int t = 0; t < T_; ++t) {
        // 1: xt
        if (tid < 96) s_xt[tid] = x[((size_t)t * B_ + b) * 96 + tid];
        __syncthreads();
        // 2: Mi += xt xt^T (regs) ; xtWq partials
        {
            float xde = s_xt[de];
            const float4* xp = (const float4*)&s_xt[ef0];
            float4 x0 = xp[0], x1 = xp[1], x2 = xp[2];
            rMi[0] += xde * x0.x; rMi[1] += xde * x0.y; rMi[2] += xde * x0.z; rMi[3] += xde * x0.w;
            rMi[4] += xde * x1.x; rMi[5] += xde * x1.y; rMi[6] += xde * x1.z; rMi[7] += xde * x1.w;
            rMi[8] += xde * x2.x; rMi[9] += xde * x2.y; rMi[10] += xde * x2.z; rMi[11] += xde * x2.w;
        }
        { int c = tid % C3, p = tid / C3; float acc = 0.f;
          for (int k = 3 * p; k < 3 * p + 3; ++k) acc += s_xt[k] * Wqkv[k * C3 + c];
          scr[tid] = acc; }
        __syncthreads();
        // 3: xtWq final ; Vtr partials (register products + shfl reduce)
        if (tid < C3) { float a = 0.f; for (int p = 0; p < 32; ++p) a += scr[p * C3 + tid]; s_xtWq[tid] = a; }
        {
            float p12[12];
#pragma unroll
            for (int ii = 0; ii < 12; ++ii) p12[ii] = rMi[ii] * rS[ii];
#pragma unroll
            for (int ii = 0; ii < 12; ++ii) {
                p12[ii] += __shfl_xor(p12[ii], 8);
                p12[ii] += __shfl_xor(p12[ii], 16);
                p12[ii] += __shfl_xor(p12[ii], 32);
            }
            if ((lane >> 3) == 0) {
#pragma unroll
                for (int ii = 0; ii < 12; ++ii)
                    scr[768 + wv * 96 + (lane & 7) * 12 + ii] = p12[ii];
            }
        }
        __syncthreads();
        // 4: Vtr final ; Q += xt ⊗ xtWq
        if (tid < 96) { float a = 0.f; for (int w = 0; w < 12; ++w) a += scr[768 + w * 96 + tid]; s_Vtr[tid] = a; }
        for (int pp = 0; pp < 3; ++pp) { int o = tid + NT * pp; int i = o / C3, c = o % C3;
            s_Q[o] += s_xt[i] * s_xtWq[c]; }
        __syncthreads();
        // 5: qkv_pre -> scr[0..2304) + LN sums
        {
            float ls = 0.f, lq = 0.f;
            for (int pp = 0; pp < 3; ++pp) {
                int o = tid + NT * pp; int i = o / C3, c = o % C3;
                float q = s_Q[o] + a2 * s_Vtr[i] * s_xtWq[c] + bqkv[c];
                scr[o] = q; ls += q; lq += q * q;
            }
            for (int off = 32; off > 0; off >>= 1) { ls += __shfl_down(ls, off); lq += __shfl_down(lq, off); }
            if (lane == 0) { s_red[wv] = ls; s_red[16 + wv] = lq; }
        }
        __syncthreads();
        if (tid == 0) {
            float S = 0.f, Qs = 0.f;
            for (int w = 0; w < 12; ++w) { S += s_red[w]; Qs += s_red[16 + w]; }
            float mu = S * (1.0f / 2304.f);
            float var = Qs * (1.0f / 2304.f) - mu * mu;
            s_mu = mu; s_rstd = rsqrtf(var + EPS_);
        }
        __syncthreads();
        // 7: LN apply
        { float mu = s_mu, rs = s_rstd;
          for (int pp = 0; pp < 3; ++pp) { int o = tid + NT * pp;
              scr[o] = (scr[o] - mu) * rs * ln_g[o] + ln_b[o]; } }
        __syncthreads();
        // 8: v copy (+bf16 dump) + t (fp32 tanh, exact tsum, split store + bf16 dump)
        { int j = tid / 96, e = tid % 96;
          float vv = scr[e * C3 + 16 + j];
          s_v[tid] = vv;
          vgb[((size_t)(t * B_ + b)) * 768 + tid] = f2bf(vv); }
        {
            int j = tid / 96, d = tid % 96;
            float kk = scr[d * C3 + 8 + j];
            float ts = 0.f;
#pragma unroll
            for (int n = 0; n < 8; ++n) {
                float tv = tanhf(scr[d * C3 + n] * kk);
                ts += tv;
                unsigned p = packsplit(tv);
                s_tP[j * TPs + n * 96 + d] = p;
                s_t2L[n * 768 + d * 8 + j] = (short)(p >> 16);
            }
            s_tsum[j * 96 + d] = ts;
        }
        __syncthreads();
        // 9a: dump t2 (coalesced 16B)
        *(uint4*)&t2g[((size_t)(t * B_ + b)) * 6144 + tid * 8] = *(const uint4*)&s_t2L[tid * 8];
        // 9b: G-GEMM (4-term split, recurrence-critical)
        {
            const int rt = wv % 6, kh = wv / 6;
            f32x4 accG = {0.f, 0.f, 0.f, 0.f};
#pragma unroll
            for (int s2 = 0; s2 < 12; ++s2) {
                int kb = kh * 12 + s2;
                unsigned pa[8] = {0,0,0,0,0,0,0,0};
                if (col < 8) {
                    const uint4* q0 = (const uint4*)&s_tP[col * TPs + kb * 32 + grp * 8];
                    uint4 x0 = q0[0], x1 = q0[1];
                    pa[0]=x0.x; pa[1]=x0.y; pa[2]=x0.z; pa[3]=x0.w;
                    pa[4]=x1.x; pa[5]=x1.y; pa[6]=x1.z; pa[7]=x1.w;
                }
                bf16x8 ah, al; unpack_frags(pa, ah, al);
                int fo = ((rt * 24 + kb) * 64 + lane) * 8;
                bf16x8 bh = *(const bf16x8*)&W2H[fo];
                bf16x8 bl = *(const bf16x8*)&W2L[fo];
                accG = mfma16(ah, bh, accG);
                accG = mfma16(al, bh, accG);
                accG = mfma16(ah, bl, accG);
                accG = mfma16(al, bl, accG);
            }
            if (kh == 0 && grp < 2) {
#pragma unroll
                for (int reg = 0; reg < 4; ++reg)
                    s_G[(grp * 4 + reg) * 96 + rt * 16 + col] = accG[reg];
            }
            __syncthreads();
            if (kh == 1 && grp < 2) {
#pragma unroll
                for (int reg = 0; reg < 4; ++reg)
                    s_G[(grp * 4 + reg) * 96 + rt * 16 + col] += accG[reg];
            }
        }
        __syncthreads();
        // 10: GWq partials + S/Mi register updates
        { int oo = tid % 192, p = tid / 192; int jg = oo / C3, cc = oo % C3;
          float a = 0.f;
          for (int f = p * 24; f < p * 24 + 24; ++f) a += s_G[jg * 96 + f] * Wqkv[f * C3 + cc];
          scr[tid] = a; }
        {
            float tj[8], vj[8];
#pragma unroll
            for (int j = 0; j < 8; ++j) { tj[j] = s_tsum[j * 96 + de]; vj[j] = s_v[j * 96 + de]; }
            float sn[12], r2[12];
#pragma unroll
            for (int ii = 0; ii < 12; ++ii) { sn[ii] = 0.f; r2[ii] = rb2[ii]; }
#pragma unroll
            for (int j = 0; j < 8; ++j) {
                const float4* vp = (const float4*)&s_v[j * 96 + ef0];
                const float4* gp = (const float4*)&s_G[j * 96 + ef0];
#pragma unroll
                for (int q4 = 0; q4 < 3; ++q4) {
                    float4 vv = vp[q4], gg = gp[q4];
                    sn[q4 * 4 + 0] += tj[j] * vv.x; sn[q4 * 4 + 1] += tj[j] * vv.y;
                    sn[q4 * 4 + 2] += tj[j] * vv.z; sn[q4 * 4 + 3] += tj[j] * vv.w;
                    r2[q4 * 4 + 0] += vj[j] * gg.x; r2[q4 * 4 + 1] += vj[j] * gg.y;
                    r2[q4 * 4 + 2] += vj[j] * gg.z; r2[q4 * 4 + 3] += vj[j] * gg.w;
                }
            }
#pragma unroll
            for (int ii = 0; ii < 12; ++ii) {
                rS[ii] = a1 * rS[ii] + sn[ii];
                rMi[ii] += a3 * r2[ii];
            }
        }
        __syncthreads();
        // 11: GWq final
        if (tid < 192) s_GWq[tid] = scr[tid] + scr[192 + tid] + scr[384 + tid] + scr[576 + tid];
        __syncthreads();
        // 12: Q += a3*(v^T GWq + b2Wq)
        for (int pp = 0; pp < 3; ++pp) {
            int o = tid + NT * pp; int i = o / C3, c = o % C3;
            float a = s_b2Wq[c];
#pragma unroll
            for (int j = 0; j < 8; ++j) a += s_v[j * 96 + i] * s_GWq[j * C3 + c];
            s_Q[o] += a3 * a;
        }
        __syncthreads();
    }
}

// ================= Kernel B: Δy, one wave per (b,t), no barriers =================
__global__ __launch_bounds__(512, 1) void dy_kernel(
    const short* __restrict__ WrBH, const short* __restrict__ WrBL,
    const short* __restrict__ t2g, const short* __restrict__ vgb,
    float* __restrict__ dY)
{
    __shared__ __attribute__((aligned(16))) short sPT[8 * 3072];  // per-wave P^T: [r][dl*8+j]
    const int w = threadIdx.x >> 6, lane = threadIdx.x & 63;
    const int col = lane & 15, grp = lane >> 4;
    const int bt = blockIdx.x * 8 + w;
    short* PT = sPT + w * 3072;

    // A-frags: v[j=col][e], 3 K-frags, held whole kernel
    bf16x8 Av[3];
#pragma unroll
    for (int kf = 0; kf < 3; ++kf) {
        FragU F;
        if (col < 8) {
            const uint4* p = (const uint4*)&vgb[((size_t)bt * 8 + col) * 96 + kf * 32 + grp * 8];
            uint4 z = p[0];
            F.u[0] = z.x; F.u[1] = z.y; F.u[2] = z.z; F.u[3] = z.w;
        } else { F.u[0] = F.u[1] = F.u[2] = F.u[3] = 0; }
        Av[kf] = F.f;
    }
    f32x4 accD[6];
#pragma unroll
    for (int rt = 0; rt < 6; ++rt) accD[rt] = (f32x4){0.f, 0.f, 0.f, 0.f};

    for (int g = 0; g < 24; ++g) {
        // GEMM-1: 4 mini-GEMMs (one per d), P^T -> wave-private LDS
        for (int dl = 0; dl < 4; ++dl) {
            const int d = g * 4 + dl;
            f32x4 acc[6];
#pragma unroll
            for (int rt = 0; rt < 6; ++rt) acc[rt] = (f32x4){0.f, 0.f, 0.f, 0.f};
#pragma unroll
            for (int kf = 0; kf < 3; ++kf) {
#pragma unroll
                for (int rt = 0; rt < 6; ++rt) {
                    size_t fo = ((size_t)(d * 18 + rt * 3 + kf) * 64 + lane) * 8;
                    bf16x8 bh = *(const bf16x8*)&WrBH[fo];
                    bf16x8 bl = *(const bf16x8*)&WrBL[fo];
                    acc[rt] = mfma16(Av[kf], bh, acc[rt]);
                    acc[rt] = mfma16(Av[kf], bl, acc[rt]);
                }
            }
            if (grp < 2) {
#pragma unroll
                for (int rt = 0; rt < 6; ++rt) {
                    unsigned u0 = (unsigned)(unsigned short)f2bf(acc[rt][0]) |
                                  ((unsigned)(unsigned short)f2bf(acc[rt][1]) << 16);
                    unsigned u1 = (unsigned)(unsigned short)f2bf(acc[rt][2]) |
                                  ((unsigned)(unsigned short)f2bf(acc[rt][3]) << 16);
                    uint2 uu; uu.x = u0; uu.y = u1;
                    *(uint2*)&PT[(rt * 16 + col) * 32 + dl * 8 + grp * 4] = uu;
                }
            }
        }
        // GEMM-2: Δy += t[:, g-group] @ P
        {
            FragU A2;
            if (col < 8) {
                const uint4* p = (const uint4*)&t2g[((size_t)bt * 8 + col) * 768 + g * 32 + grp * 8];
                uint4 z = p[0];
                A2.u[0] = z.x; A2.u[1] = z.y; A2.u[2] = z.z; A2.u[3] = z.w;
            } else { A2.u[0] = A2.u[1] = A2.u[2] = A2.u[3] = 0; }
#pragma unroll
            for (int rt = 0; rt < 6; ++rt) {
                bf16x8 B2 = *(const bf16x8*)&PT[(rt * 16 + col) * 32 + grp * 8];
                accD[rt] = mfma16(A2.f, B2, accD[rt]);
            }
        }
    }
    if (grp < 2) {
#pragma unroll
        for (int rt = 0; rt < 6; ++rt)
#pragma unroll
            for (int reg = 0; reg < 4; ++reg)
                dY[(size_t)bt * 768 + (grp * 4 + reg) * 96 + rt * 16 + col] = accD[rt][reg];
    }
}

// ================= Kernel D: y-scan + out GEMM, 1 block per batch =================
__global__ __launch_bounds__(NT, 1) void out_kernel(
    const float* __restrict__ dY, const float* __restrict__ y0g, const float* __restrict__ a1p,
    const float* __restrict__ br, const float* __restrict__ W3, const float* __restrict__ b3,
    float* __restrict__ out)
{
    __shared__ float s_r[768];
    __shared__ float s_p[768];
    const int tid = threadIdx.x, b = blockIdx.x;
    const float a1 = a1p[0];
    float y = y0g[tid];
    const float brv = br[tid % 96];
    const int o = tid & 63, q = tid >> 6;
    for (int t = 0; t < T_; ++t) {
        y = a1 * y + dY[((size_t)(t * B_ + b)) * 768 + tid];
        s_r[tid] = y + brv;
        __syncthreads();
        float a = 0.f;
        for (int i = q * 64; i < q * 64 + 64; ++i)
            a += s_r[i] * W3[(size_t)i * 64 + o];
        s_p[tid] = a;
        __syncthreads();
        if (tid < 64) {
            float acc = b3[tid];
            for (int qq = 0; qq < 12; ++qq) acc += s_p[qq * 64 + tid];
            out[((size_t)(t * B_ + b)) * OUT_ + tid] = acc;
        }
        __syncthreads();
    }
}

extern "C" void kernel_launch(void* const* d_in, const int* in_sizes, int n_in,
                              void* d_out, int out_size, void* d_ws, size_t ws_size,
                              hipStream_t stream) {
    const float* x         = (const float*)d_in[0];
    const float* Wqkv      = (const float*)d_in[1];
    const float* bqkv      = (const float*)d_in[2];
    const float* ln_g      = (const float*)d_in[3];
    const float* ln_b      = (const float*)d_in[4];
    const float* a1        = (const float*)d_in[5];
    const float* a2        = (const float*)d_in[6];
    const float* a3        = (const float*)d_in[7];
    const float* W2        = (const float*)d_in[8];
    const float* b2        = (const float*)d_in[9];
    const float* Wr        = (const float*)d_in[10];
    const float* br        = (const float*)d_in[11];
    const float* W3        = (const float*)d_in[12];
    const float* b3        = (const float*)d_in[13];
    const float* item_bias = (const float*)d_in[14];
    const float* rel_bias  = (const float*)d_in[15];
    float* out = (float*)d_out;

    char* ws = (char*)d_ws;
    short* WrBH = (short*)ws;                          // 1,769,472 B
    short* WrBL = (short*)(ws + 1769472);              // 1,769,472 B
    short* W2H  = (short*)(ws + 3538944);              //   147,456 B
    short* W2L  = (short*)(ws + 3686400);              //   147,456 B
    float* y0   = (float*)(ws + 3833856);              //     3,072 B
    short* t2g  = (short*)(ws + 3840000);              // 25,165,824 B
    short* vgb  = (short*)(ws + 29005824);             //  3,145,728 B
    float* dY   = (float*)(ws + 32151552);             //  6,291,456 B  (total ~38.4 MB)

    hipLaunchKernelGGL(prep_wrB, dim3(3456), dim3(256), 0, stream, Wr, WrBH, WrBL);
    hipLaunchKernelGGL(prep_w2f, dim3(288), dim3(256), 0, stream, W2, W2H, W2L);
    hipLaunchKernelGGL(y0_kernel, dim3(8), dim3(NT), 0, stream, rel_bias, Wr, y0);
    hipLaunchKernelGGL(stm_rec, dim3(B_), dim3(NT), 0, stream,
                       x, Wqkv, bqkv, ln_g, ln_b, a1, a2, a3,
                       b2, item_bias, rel_bias, W2H, W2L, t2g, vgb);
    hipLaunchKernelGGL(dy_kernel, dim3(256), dim3(512), 0, stream,
                       WrBH, WrBL, t2g, vgb, dY);
    hipLaunchKernelGGL(out_kernel, dim3(B_), dim3(NT), 0, stream,
                       dY, y0, a1, br, W3, b3, out);
}

// Round 8
// 1129.930 us; speedup vs baseline: 2.8906x; 1.2300x over previous
//
#include <hip/hip_runtime.h>
#include <math.h>

#define T_ 16
#define B_ 128
#define C3 24
#define OUT_ 64
#define NT 768
#define EPS_ 1e-5f
#define TPs 776      // s_tP row stride (dwords)

typedef __attribute__((ext_vector_type(8))) short bf16x8;
typedef __attribute__((ext_vector_type(4))) float f32x4;

union FragU { unsigned u[4]; bf16x8 f; };

__device__ __forceinline__ short f2bf(float x) {
    unsigned u = __float_as_uint(x);
    return (short)((u + 0x7fffu + ((u >> 16) & 1u)) >> 16);
}
// fp32 -> (bf16_hi << 16) | bf16_lo(residual), both RNE
__device__ __forceinline__ unsigned packsplit(float x) {
    unsigned u = __float_as_uint(x);
    unsigned h = (u + 0x7fffu + ((u >> 16) & 1u)) & 0xffff0000u;
    float r = x - __uint_as_float(h);
    unsigned v = __float_as_uint(r);
    unsigned l = (v + 0x7fffu + ((v >> 16) & 1u)) >> 16;
    return h | l;
}
__device__ __forceinline__ void unpack_frags(const unsigned* p, bf16x8& hi, bf16x8& lo) {
    FragU H, L;
#pragma unroll
    for (int q = 0; q < 4; ++q) {
        H.u[q] = (p[2*q] >> 16) | (p[2*q+1] & 0xffff0000u);
        L.u[q] = (p[2*q] & 0xffffu) | (p[2*q+1] << 16);
    }
    hi = H.f; lo = L.f;
}
__device__ __forceinline__ f32x4 mfma16(bf16x8 a, bf16x8 b, f32x4 c) {
    return __builtin_amdgcn_mfma_f32_16x16x32_bf16(a, b, c, 0, 0, 0);
}

// ---------- prep: Wr -> B-fragment-major hi/lo planes, per-d mini-GEMMs ----------
// frag f = d*18 + rt*3 + kf ; element = Wr[(d*96 + kf*32+grp*8+jj)][rt*16+col]
__global__ void prep_wrB(const float* __restrict__ Wr, short* __restrict__ H, short* __restrict__ L) {
    int idx = blockIdx.x * 256 + threadIdx.x;
    if (idx >= 884736) return;
    int jj = idx & 7, lane = (idx >> 3) & 63, f = idx >> 9;
    int kf = f % 3, rt = (f / 3) % 6, d = f / 18;
    int col = lane & 15, grp = lane >> 4;
    int e = kf * 32 + grp * 8 + jj;
    int r = rt * 16 + col;
    float x = Wr[(size_t)(d * 96 + e) * 96 + r];
    unsigned u = __float_as_uint(x);
    unsigned hb = (u + 0x7fffu + ((u >> 16) & 1u)) & 0xffff0000u;
    float res = x - __uint_as_float(hb);
    unsigned v = __float_as_uint(res);
    H[idx] = (short)(hb >> 16);
    L[idx] = (short)((v + 0x7fffu + ((v >> 16) & 1u)) >> 16);
}
// ---------- prep: W2 -> B-fragment-major hi/lo planes (for G-GEMM) ----------
__global__ void prep_w2f(const float* __restrict__ W2, short* __restrict__ Fhi, short* __restrict__ Flo) {
    int idx = blockIdx.x * 256 + threadIdx.x;
    if (idx >= 73728) return;
    int j = idx & 7, lane = (idx >> 3) & 63, kb = (idx >> 9) % 24, rt = idx / (512 * 24);
    int col = lane & 15, grp = lane >> 4;
    int f = rt * 16 + col, k = kb * 32 + grp * 8 + j;
    float x = W2[(size_t)k * 96 + f];
    unsigned u = __float_as_uint(x);
    unsigned h = (u + 0x7fffu + ((u >> 16) & 1u)) & 0xffff0000u;
    float res = x - __uint_as_float(h);
    unsigned v = __float_as_uint(res);
    Fhi[idx] = (short)(h >> 16);
    Flo[idx] = (short)((v + 0x7fffu + ((v >> 16) & 1u)) >> 16);
}
// ---------- prep: y0 = rel_bias @ Wr (fp32), 64-block atomic version ----------
__global__ __launch_bounds__(NT, 1) void y0_kernel(const float* __restrict__ rel_bias,
                                                   const float* __restrict__ Wr,
                                                   float* __restrict__ y0) {
    __shared__ float s[NT];
    const int n = blockIdx.x >> 3, sl = blockIdx.x & 7;
    const int tid = threadIdx.x;
    const int r = tid % 96, p = tid / 96;
    const float* rb = rel_bias + n * 9216 + sl * 1152;
    float acc = 0.f;
    for (int i = p * 144; i < p * 144 + 144; ++i)
        acc += rb[i] * Wr[(size_t)(sl * 1152 + i) * 96 + r];
    s[tid] = acc;
    __syncthreads();
    if (tid < 96) {
        float tot = 0.f;
        for (int q = 0; q < 8; ++q) tot += s[q * 96 + tid];
        atomicAdd(&y0[n * 96 + tid], tot);
    }
}

// ================= Kernel A: recurrence only, 1 block per batch =================
__global__ __launch_bounds__(NT, 2) void stm_rec(
    const float* __restrict__ x, const float* __restrict__ Wqkv, const float* __restrict__ bqkv,
    const float* __restrict__ ln_g, const float* __restrict__ ln_b,
    const float* __restrict__ a1p, const float* __restrict__ a2p, const float* __restrict__ a3p,
    const float* __restrict__ b2,
    const float* __restrict__ item_bias, const float* __restrict__ rel_bias,
    const short* __restrict__ W2H, const short* __restrict__ W2L,
    short* __restrict__ t2g, short* __restrict__ vgb)
{
    __shared__ float s_Q[2304];
    __shared__ __attribute__((aligned(16))) unsigned s_scr[2304];
    __shared__ __attribute__((aligned(16))) unsigned s_tP[8 * TPs]; // split t: [j][n*96+d]
    __shared__ __attribute__((aligned(16))) short s_t2L[6144];      // bf16 t: [n][d*8+j]
    __shared__ float s_Wq[2304];
    __shared__ float s_lng[2304];
    __shared__ float s_lnb[2304];
    __shared__ float s_tsum[768];
    __shared__ float s_v[768];
    __shared__ float s_G[768];
    __shared__ float s_xt[96];
    __shared__ float s_xtWq[24];
    __shared__ float s_GWq[192];
    __shared__ float s_b2Wq[24];
    __shared__ float s_bq[24];
    __shared__ float s_Vtr[96];
    __shared__ float s_red[32];

    const int tid = threadIdx.x;
    const int b = blockIdx.x;
    const int wv = tid >> 6, lane = tid & 63, col = lane & 15, grp = lane >> 4;
    const float a1 = a1p[0], a2 = a2p[0], a3 = a3p[0];
    float* scr = (float*)s_scr;

    // register-resident Mi/S: thread owns (de, ef0..ef0+12)
    const int de = tid >> 3, ef0 = (tid & 7) * 12;
    float rMi[12], rS[12], rb2[12];
#pragma unroll
    for (int ii = 0; ii < 12; ++ii) {
        rMi[ii] = item_bias[de * 96 + ef0 + ii];
        float ss = 0.f;
        for (int n = 0; n < 8; ++n) ss += rel_bias[n * 9216 + de * 96 + ef0 + ii];
        rS[ii] = ss;
        rb2[ii] = b2[ef0 + ii];
    }

    // ---- init: stage small weights in LDS ----
    for (int i = tid; i < 2304; i += NT) {
        s_Wq[i] = Wqkv[i];
        s_lng[i] = ln_g[i];
        s_lnb[i] = ln_b[i];
    }
    if (tid < 24) s_bq[tid] = bqkv[tid];
    __syncthreads();
    for (int pp = 0; pp < 3; ++pp) {
        int o = tid + NT * pp; int i = o / C3, c = o % C3;
        float acc = 0.f;
        const float* ib = item_bias + i * 96;
        for (int k = 0; k < 96; ++k) acc += ib[k] * s_Wq[k * C3 + c];
        s_Q[o] = acc;
    }
    { int c = tid % C3, p = tid / C3; float acc = 0.f;
      for (int k = 3 * p; k < 3 * p + 3; ++k) acc += b2[k] * s_Wq[k * C3 + c];
      scr[tid] = acc; }
    __syncthreads();
    if (tid < C3) { float a = 0.f; for (int p = 0; p < 32; ++p) a += scr[p * C3 + tid]; s_b2Wq[tid] = a; }
    __syncthreads();

    for (int t = 0; t < T_; ++t) {
        // 1: xt
        if (tid < 96) s_xt[tid] = x[((size_t)t * B_ + b) * 96 + tid];
        __syncthreads();
        // 2: Mi += xt xt^T (regs) ; xtWq partials
        {
            float xde = s_xt[de];
            const float4* xp = (const float4*)&s_xt[ef0];
            float4 x0 = xp[0], x1 = xp[1], x2 = xp[2];
            rMi[0] += xde * x0.x; rMi[1] += xde * x0.y; rMi[2] += xde * x0.z; rMi[3] += xde * x0.w;
            rMi[4] += xde * x1.x; rMi[5] += xde * x1.y; rMi[6] += xde * x1.z; rMi[7] += xde * x1.w;
            rMi[8] += xde * x2.x; rMi[9] += xde * x2.y; rMi[10] += xde * x2.z; rMi[11] += xde * x2.w;
        }
        { int c = tid % C3, p = tid / C3; float acc = 0.f;
          for (int k = 3 * p; k < 3 * p + 3; ++k) acc += s_xt[k] * s_Wq[k * C3 + c];
          scr[tid] = acc; }
        __syncthreads();
        // 3: xtWq final ; Vtr partials (register products + shfl reduce)
        if (tid < C3) { float a = 0.f; for (int p = 0; p < 32; ++p) a += scr[p * C3 + tid]; s_xtWq[tid] = a; }
        {
            float p12[12];
#pragma unroll
            for (int ii = 0; ii < 12; ++ii) p12[ii] = rMi[ii] * rS[ii];
#pragma unroll
            for (int ii = 0; ii < 12; ++ii) {
                p12[ii] += __shfl_xor(p12[ii], 8);
                p12[ii] += __shfl_xor(p12[ii], 16);
                p12[ii] += __shfl_xor(p12[ii], 32);
            }
            if ((lane >> 3) == 0) {
#pragma unroll
                for (int ii = 0; ii < 12; ++ii)
                    scr[768 + wv * 96 + (lane & 7) * 12 + ii] = p12[ii];
            }
        }
        __syncthreads();
        // 4: Vtr final ; Q += xt ⊗ xtWq
        if (tid < 96) { float a = 0.f; for (int w = 0; w < 12; ++w) a += scr[768 + w * 96 + tid]; s_Vtr[tid] = a; }
        for (int pp = 0; pp < 3; ++pp) { int o = tid + NT * pp; int i = o / C3, c = o % C3;
            s_Q[o] += s_xt[i] * s_xtWq[c]; }
        __syncthreads();
        // 5: qkv_pre -> scr[0..2304) + LN sums
        {
            float ls = 0.f, lq = 0.f;
            for (int pp = 0; pp < 3; ++pp) {
                int o = tid + NT * pp; int i = o / C3, c = o % C3;
                float q = s_Q[o] + a2 * s_Vtr[i] * s_xtWq[c] + s_bq[c];
                scr[o] = q; ls += q; lq += q * q;
            }
            for (int off = 32; off > 0; off >>= 1) { ls += __shfl_down(ls, off); lq += __shfl_down(lq, off); }
            if (lane == 0) { s_red[wv] = ls; s_red[16 + wv] = lq; }
        }
        __syncthreads();
        // 6+7: mu/rstd computed redundantly by every thread; LN apply (no extra barrier)
        {
            float S = 0.f, Qs = 0.f;
            for (int w = 0; w < 12; ++w) { S += s_red[w]; Qs += s_red[16 + w]; }
            float mu = S * (1.0f / 2304.f);
            float rstd = rsqrtf(Qs * (1.0f / 2304.f) - mu * mu + EPS_);
            for (int pp = 0; pp < 3; ++pp) {
                int o = tid + NT * pp;
                scr[o] = (scr[o] - mu) * rstd * s_lng[o] + s_lnb[o];
            }
        }
        __syncthreads();
        // 8: v copy (+bf16 dump) + t (fp32 tanh, exact tsum, split store + bf16 dump)
        { int j = tid / 96, e = tid % 96;
          float vv = scr[e * C3 + 16 + j];
          s_v[tid] = vv;
          vgb[((size_t)(t * B_ + b)) * 768 + tid] = f2bf(vv); }
        {
            int j = tid / 96, d = tid % 96;
            float kk = scr[d * C3 + 8 + j];
            float ts = 0.f;
#pragma unroll
            for (int n = 0; n < 8; ++n) {
                float tv = tanhf(scr[d * C3 + n] * kk);
                ts += tv;
                unsigned p = packsplit(tv);
                s_tP[j * TPs + n * 96 + d] = p;
                s_t2L[n * 768 + d * 8 + j] = (short)(p >> 16);
            }
            s_tsum[j * 96 + d] = ts;
        }
        __syncthreads();
        // 9a: dump t2 (coalesced 16B)
        *(uint4*)&t2g[((size_t)(t * B_ + b)) * 6144 + tid * 8] = *(const uint4*)&s_t2L[tid * 8];
        // 9b: G-GEMM (4-term split, recurrence-critical)
        {
            const int rt = wv % 6, kh = wv / 6;
            f32x4 accG = {0.f, 0.f, 0.f, 0.f};
#pragma unroll
            for (int s2 = 0; s2 < 12; ++s2) {
                int kb = kh * 12 + s2;
                unsigned pa[8] = {0,0,0,0,0,0,0,0};
                if (col < 8) {
                    const uint4* q0 = (const uint4*)&s_tP[col * TPs + kb * 32 + grp * 8];
                    uint4 x0 = q0[0], x1 = q0[1];
                    pa[0]=x0.x; pa[1]=x0.y; pa[2]=x0.z; pa[3]=x0.w;
                    pa[4]=x1.x; pa[5]=x1.y; pa[6]=x1.z; pa[7]=x1.w;
                }
                bf16x8 ah, al; unpack_frags(pa, ah, al);
                int fo = ((rt * 24 + kb) * 64 + lane) * 8;
                bf16x8 bh = *(const bf16x8*)&W2H[fo];
                bf16x8 bl = *(const bf16x8*)&W2L[fo];
                accG = mfma16(ah, bh, accG);
                accG = mfma16(al, bh, accG);
                accG = mfma16(ah, bl, accG);
                accG = mfma16(al, bl, accG);
            }
            if (kh == 0 && grp < 2) {
#pragma unroll
                for (int reg = 0; reg < 4; ++reg)
                    s_G[(grp * 4 + reg) * 96 + rt * 16 + col] = accG[reg];
            }
            __syncthreads();
            if (kh == 1 && grp < 2) {
#pragma unroll
                for (int reg = 0; reg < 4; ++reg)
                    s_G[(grp * 4 + reg) * 96 + rt * 16 + col] += accG[reg];
            }
        }
        __syncthreads();
        // 10: GWq partials + S/Mi register updates
        { int oo = tid % 192, p = tid / 192; int jg = oo / C3, cc = oo % C3;
          float a = 0.f;
          for (int f = p * 24; f < p * 24 + 24; ++f) a += s_G[jg * 96 + f] * s_Wq[f * C3 + cc];
          scr[tid] = a; }
        {
            float tj[8], vj[8];
#pragma unroll
            for (int j = 0; j < 8; ++j) { tj[j] = s_tsum[j * 96 + de]; vj[j] = s_v[j * 96 + de]; }
            float sn[12], r2[12];
#pragma unroll
            for (int ii = 0; ii < 12; ++ii) { sn[ii] = 0.f; r2[ii] = rb2[ii]; }
#pragma unroll
            for (int j = 0; j < 8; ++j) {
                const float4* vp = (const float4*)&s_v[j * 96 + ef0];
                const float4* gp = (const float4*)&s_G[j * 96 + ef0];
#pragma unroll
                for (int q4 = 0; q4 < 3; ++q4) {
                    float4 vv = vp[q4], gg = gp[q4];
                    sn[q4 * 4 + 0] += tj[j] * vv.x; sn[q4 * 4 + 1] += tj[j] * vv.y;
                    sn[q4 * 4 + 2] += tj[j] * vv.z; sn[q4 * 4 + 3] += tj[j] * vv.w;
                    r2[q4 * 4 + 0] += vj[j] * gg.x; r2[q4 * 4 + 1] += vj[j] * gg.y;
                    r2[q4 * 4 + 2] += vj[j] * gg.z; r2[q4 * 4 + 3] += vj[j] * gg.w;
                }
            }
#pragma unroll
            for (int ii = 0; ii < 12; ++ii) {
                rS[ii] = a1 * rS[ii] + sn[ii];
                rMi[ii] += a3 * r2[ii];
            }
        }
        __syncthreads();
        // 11: GWq final
        if (tid < 192) s_GWq[tid] = scr[tid] + scr[192 + tid] + scr[384 + tid] + scr[576 + tid];
        __syncthreads();
        // 12: Q += a3*(v^T GWq + b2Wq)
        for (int pp = 0; pp < 3; ++pp) {
            int o = tid + NT * pp; int i = o / C3, c = o % C3;
            float a = s_b2Wq[c];
#pragma unroll
            for (int j = 0; j < 8; ++j) a += s_v[j * 96 + i] * s_GWq[j * C3 + c];
            s_Q[o] += a3 * a;
        }
        __syncthreads();
    }
}

// ================= Kernel B: Δy — LDS-staged Wr, 4 bt per wave =================
__global__ __launch_bounds__(128, 1) void dy_kernel(
    const short* __restrict__ WrBH, const short* __restrict__ WrBL,
    const short* __restrict__ t2g, const short* __restrict__ vgb,
    float* __restrict__ dY)
{
    __shared__ __attribute__((aligned(16))) short sW[2][18432];   // [buf][hi 9216 | lo 9216]
    __shared__ __attribute__((aligned(16))) short sPT[8][3072];   // [w*4+btl][r*32 + dl*8 + j]
    const int tid = threadIdx.x;
    const int w = tid >> 6, lane = tid & 63, col = lane & 15, grp = lane >> 4;
    const int bt0 = blockIdx.x * 8 + w * 4;

    // A-frags: v[j=col][e] for 4 bt, 3 K-frags each
    bf16x8 Av[4][3];
#pragma unroll
    for (int btl = 0; btl < 4; ++btl)
#pragma unroll
        for (int kf = 0; kf < 3; ++kf) {
            FragU F;
            if (col < 8) {
                uint4 z = *(const uint4*)&vgb[((size_t)(bt0 + btl)) * 768 + col * 96 + kf * 32 + grp * 8];
                F.u[0] = z.x; F.u[1] = z.y; F.u[2] = z.z; F.u[3] = z.w;
            } else { F.u[0] = F.u[1] = F.u[2] = F.u[3] = 0; }
            Av[btl][kf] = F.f;
        }
    f32x4 accD[4][6];
#pragma unroll
    for (int btl = 0; btl < 4; ++btl)
#pragma unroll
        for (int rt = 0; rt < 6; ++rt) accD[btl][rt] = (f32x4){0.f, 0.f, 0.f, 0.f};

    // stage d=0 into buf 0
    {
        const uint4* sH = (const uint4*)WrBH;
        const uint4* sL = (const uint4*)WrBL;
        uint4* dst = (uint4*)sW[0];
#pragma unroll
        for (int i = 0; i < 18; ++i) {
            int idx = i * 128 + tid;
            dst[idx] = (idx < 1152) ? sH[idx] : sL[idx - 1152];
        }
    }
    __syncthreads();

    uint4 a2r[4];
    for (int d = 0; d < 96; ++d) {
        const int buf = d & 1, dl = d & 3, g = d >> 2;
        // prefetch-stage d+1 into the other buffer (overlaps with consume)
        if (d + 1 < 96) {
            const uint4* sH = (const uint4*)(WrBH + (size_t)(d + 1) * 9216);
            const uint4* sL = (const uint4*)(WrBL + (size_t)(d + 1) * 9216);
            uint4* dst = (uint4*)sW[buf ^ 1];
#pragma unroll
            for (int i = 0; i < 18; ++i) {
                int idx = i * 128 + tid;
                dst[idx] = (idx < 1152) ? sH[idx] : sL[idx - 1152];
            }
        }
        // prefetch A2 fragments at group start
        if (dl == 0) {
#pragma unroll
            for (int btl = 0; btl < 4; ++btl) {
                if (col < 8)
                    a2r[btl] = *(const uint4*)&t2g[((size_t)(bt0 + btl)) * 6144 + col * 768 + g * 32 + grp * 8];
                else { a2r[btl].x = a2r[btl].y = a2r[btl].z = a2r[btl].w = 0; }
            }
        }
        // GEMM-1: P_d = v @ Wr_d (hi+lo split), 4 bt per wave share every B-frag
        f32x4 aP[4][6];
#pragma unroll
        for (int btl = 0; btl < 4; ++btl)
#pragma unroll
            for (int rt = 0; rt < 6; ++rt) aP[btl][rt] = (f32x4){0.f, 0.f, 0.f, 0.f};
        const short* W = sW[buf];
#pragma unroll
        for (int kf = 0; kf < 3; ++kf)
#pragma unroll
            for (int rt = 0; rt < 6; ++rt) {
                bf16x8 bh = *(const bf16x8*)&W[((rt * 3 + kf) * 64 + lane) * 8];
                bf16x8 bl = *(const bf16x8*)&W[9216 + ((rt * 3 + kf) * 64 + lane) * 8];
#pragma unroll
                for (int btl = 0; btl < 4; ++btl) {
                    aP[btl][rt] = mfma16(Av[btl][kf], bh, aP[btl][rt]);
                    aP[btl][rt] = mfma16(Av[btl][kf], bl, aP[btl][rt]);
                }
            }
        // pack P_d into wave-private PT
        if (grp < 2) {
#pragma unroll
            for (int btl = 0; btl < 4; ++btl)
#pragma unroll
                for (int rt = 0; rt < 6; ++rt) {
                    uint2 uu;
                    uu.x = (unsigned)(unsigned short)f2bf(aP[btl][rt][0]) |
                           ((unsigned)(unsigned short)f2bf(aP[btl][rt][1]) << 16);
                    uu.y = (unsigned)(unsigned short)f2bf(aP[btl][rt][2]) |
                           ((unsigned)(unsigned short)f2bf(aP[btl][rt][3]) << 16);
                    *(uint2*)&sPT[w * 4 + btl][(rt * 16 + col) * 32 + dl * 8 + grp * 4] = uu;
                }
        }
        // GEMM-2 every 4 d's: Δy += t @ P
        if (dl == 3) {
#pragma unroll
            for (int btl = 0; btl < 4; ++btl) {
                FragU A2;
                A2.u[0] = a2r[btl].x; A2.u[1] = a2r[btl].y; A2.u[2] = a2r[btl].z; A2.u[3] = a2r[btl].w;
#pragma unroll
                for (int rt = 0; rt < 6; ++rt) {
                    bf16x8 B2 = *(const bf16x8*)&sPT[w * 4 + btl][(rt * 16 + col) * 32 + grp * 8];
                    accD[btl][rt] = mfma16(A2.f, B2, accD[btl][rt]);
                }
            }
        }
        __syncthreads();
    }
    // write dY [bt][n][r]
    if (grp < 2) {
#pragma unroll
        for (int btl = 0; btl < 4; ++btl)
#pragma unroll
            for (int rt = 0; rt < 6; ++rt)
#pragma unroll
                for (int reg = 0; reg < 4; ++reg)
                    dY[((size_t)(bt0 + btl)) * 768 + (grp * 4 + reg) * 96 + rt * 16 + col] = accD[btl][rt][reg];
    }
}

// ================= Kernel D: y-scan + out GEMM, 1 block per batch =================
__global__ __launch_bounds__(NT, 1) void out_kernel(
    const float* __restrict__ dY, const float* __restrict__ y0g, const float* __restrict__ a1p,
    const float* __restrict__ br, const float* __restrict__ W3, const float* __restrict__ b3,
    float* __restrict__ out)
{
    __shared__ float s_r[768];
    __shared__ float s_p[768];
    const int tid = threadIdx.x, b = blockIdx.x;
    const float a1 = a1p[0];
    float y = y0g[tid];
    const float brv = br[tid % 96];
    const int o = tid & 63, q = tid >> 6;
    for (int t = 0; t < T_; ++t) {
        y = a1 * y + dY[((size_t)(t * B_ + b)) * 768 + tid];
        s_r[tid] = y + brv;
        __syncthreads();
        float a = 0.f;
        for (int i = q * 64; i < q * 64 + 64; ++i)
            a += s_r[i] * W3[(size_t)i * 64 + o];
        s_p[tid] = a;
        __syncthreads();
        if (tid < 64) {
            float acc = b3[tid];
            for (int qq = 0; qq < 12; ++qq) acc += s_p[qq * 64 + tid];
            out[((size_t)(t * B_ + b)) * OUT_ + tid] = acc;
        }
        __syncthreads();
    }
}

extern "C" void kernel_launch(void* const* d_in, const int* in_sizes, int n_in,
                              void* d_out, int out_size, void* d_ws, size_t ws_size,
                              hipStream_t stream) {
    const float* x         = (const float*)d_in[0];
    const float* Wqkv      = (const float*)d_in[1];
    const float* bqkv      = (const float*)d_in[2];
    const float* ln_g      = (const float*)d_in[3];
    const float* ln_b      = (const float*)d_in[4];
    const float* a1        = (const float*)d_in[5];
    const float* a2        = (const float*)d_in[6];
    const float* a3        = (const float*)d_in[7];
    const float* W2        = (const float*)d_in[8];
    const float* b2        = (const float*)d_in[9];
    const float* Wr        = (const float*)d_in[10];
    const float* br        = (const float*)d_in[11];
    const float* W3        = (const float*)d_in[12];
    const float* b3        = (const float*)d_in[13];
    const float* item_bias = (const float*)d_in[14];
    const float* rel_bias  = (const float*)d_in[15];
    float* out = (float*)d_out;

    char* ws = (char*)d_ws;
    short* WrBH = (short*)ws;                          // 1,769,472 B
    short* WrBL = (short*)(ws + 1769472);              // 1,769,472 B
    short* W2H  = (short*)(ws + 3538944);              //   147,456 B
    short* W2L  = (short*)(ws + 3686400);              //   147,456 B
    float* y0   = (float*)(ws + 3833856);              //     3,072 B
    short* t2g  = (short*)(ws + 3840000);              // 25,165,824 B
    short* vgb  = (short*)(ws + 29005824);             //  3,145,728 B
    float* dY   = (float*)(ws + 32151552);             //  6,291,456 B

    hipMemsetAsync(y0, 0, 3072, stream);
    hipLaunchKernelGGL(prep_wrB, dim3(3456), dim3(256), 0, stream, Wr, WrBH, WrBL);
    hipLaunchKernelGGL(prep_w2f, dim3(288), dim3(256), 0, stream, W2, W2H, W2L);
    hipLaunchKernelGGL(y0_kernel, dim3(64), dim3(NT), 0, stream, rel_bias, Wr, y0);
    hipLaunchKernelGGL(stm_rec, dim3(B_), dim3(NT), 0, stream,
                       x, Wqkv, bqkv, ln_g, ln_b, a1, a2, a3,
                       b2, item_bias, rel_bias, W2H, W2L, t2g, vgb);
    hipLaunchKernelGGL(dy_kernel, dim3(256), dim3(128), 0, stream,
                       WrBH, WrBL, t2g, vgb, dY);
    hipLaunchKernelGGL(out_kernel, dim3(B_), dim3(NT), 0, stream,
                       dY, y0, a1, br, W3, b3, out);
}